// Round 2
// baseline (64.294 us; speedup 1.0000x reference)
//
#include <hip/hip_runtime.h>
#include <math.h>

// Shapes (hard-coded per reference setup_inputs):
//   b=16, t=128, c=t-1=127, kv_dim=k=64, h=4, q_dim=256
#define Bdim 16
#define Tdim 128
#define Cdim 127
#define Hdim 4
#define QD   256
#define HK   256   // h*k

// K1: M[i, h*64+m] = sum_j Wq[i,h*64+j] * Wk[m,h*64+j]
// lane = j (the summed index): both Wq and Wk reads fully coalesced.
// Wave-reduce per m via shfl_xor; lane m keeps the result.
__global__ __launch_bounds__(256) void precompute_M(
        const float* __restrict__ Wq, const float* __restrict__ Wk,
        float* __restrict__ M) {
    int i = blockIdx.x;          // 0..255 (q_dim)
    int tid = threadIdx.x;
    int h = tid >> 6, lane = tid & 63;
    float q = Wq[i * HK + h * 64 + lane];        // coalesced
    float r = 0.f;
    for (int m = 0; m < 64; ++m) {
        float p = q * Wk[m * HK + h * 64 + lane];  // coalesced, L2-hot
        #pragma unroll
        for (int mask = 32; mask >= 1; mask >>= 1)
            p += __shfl_xor(p, mask, 64);
        if (m == lane) r = p;
    }
    M[i * HK + h * 64 + lane] = r;               // coalesced
}

// K2: qk[bt, :] = q_x[bt, :] @ M   ([2048,256] @ [256,256])
// 256 blocks x 256 threads; 8 rows/block; float4 LDS broadcasts, 4-wide i-unroll.
__global__ __launch_bounds__(256) void qk_gemm(
        const float* __restrict__ q_x,
        const float* __restrict__ M,
        float* __restrict__ qk) {
    __shared__ __align__(16) float4 qls[8][64];   // 8 rows x 256 floats
    int blk = blockIdx.x;
    int tid = threadIdx.x;
    const float4* src = (const float4*)(q_x + (size_t)blk * 8 * QD);
    ((float4*)qls)[tid]       = src[tid];
    ((float4*)qls)[tid + 256] = src[tid + 256];
    __syncthreads();
    float acc[8] = {0.f,0.f,0.f,0.f,0.f,0.f,0.f,0.f};
    #pragma unroll 4
    for (int i4 = 0; i4 < 64; ++i4) {
        float m0 = M[(4*i4+0) * HK + tid];        // coalesced, L2-hot
        float m1 = M[(4*i4+1) * HK + tid];
        float m2 = M[(4*i4+2) * HK + tid];
        float m3 = M[(4*i4+3) * HK + tid];
        #pragma unroll
        for (int r = 0; r < 8; ++r) {
            float4 qv = qls[r][i4];               // b128 broadcast
            acc[r] = fmaf(qv.x, m0, fmaf(qv.y, m1, fmaf(qv.z, m2, fmaf(qv.w, m3, acc[r]))));
        }
    }
    float* dst = qk + (size_t)blk * 8 * HK;
    #pragma unroll
    for (int r = 0; r < 8; ++r) dst[r * HK + tid] = acc[r];
}

// K3: per (b,t) block — scores, softmax, context contraction, V-proj.
// X stored ROW-major in LDS as float4 chunks with XOR slot swizzle:
//   phys_slot = log_slot ^ (c & 7)   (16 slots of 16B per row)
// Access-pattern bank audit:
//   - staging: linear b128 writes, 8 disjoint 4-bank groups  -> optimal
//   - scores:  per-lane row b128 reads, groups (s^ (c&7))&7  -> 8 disjoint groups
//   - wx:      per-lane column b32 reads, full bank permutation -> 2-way (free)
__global__ __launch_bounds__(256) void attn_main(
        const float* __restrict__ kv_x,
        const float* __restrict__ qk_all,
        const float* __restrict__ Wv,
        float* __restrict__ out) {
    __shared__ __align__(16) float4 sX4[128 * 16];  // 32 KB; row 127 = zero pad
    __shared__ float qk_s[HK];
    __shared__ float w_lds[Hdim * 128];
    __shared__ float wx_lds[Hdim * 64];

    int bt  = blockIdx.x;
    int tid = threadIdx.x;
    int h = tid >> 6, lane = tid & 63;

    // Stage kv_x[b,t] (127 rows x 16 chunks) with pre-swizzled global source.
    const float4* Xg = (const float4*)(kv_x + (size_t)bt * (Cdim * 64));
    #pragma unroll
    for (int it = 0; it < 8; ++it) {
        int l = tid + it * 256;                 // LDS chunk index (linear)
        if (l < Cdim * 16) {
            int c = l >> 4, p = l & 15;
            sX4[l] = Xg[(c << 4) + (p ^ (c & 7))];
        }
    }
    if (tid < 64) ((float*)sX4)[Cdim * 64 + tid] = 0.f;   // zero pad row 127
    qk_s[tid] = qk_all[(size_t)bt * HK + tid];
    __syncthreads();

    // ---- scores: lane handles c0 = lane, c1 = lane+64 ----
    int c0 = lane, c1 = lane + 64;
    int sw = lane & 7;                           // (c0&7) == (c1&7)
    float s0 = 0.f, s1 = 0.f;
    {
        const float4* qrow = (const float4*)(qk_s + h * 64);
        const float4* x0p = sX4 + c0 * 16;
        const float4* x1p = sX4 + c1 * 16;
        #pragma unroll 4
        for (int s = 0; s < 16; ++s) {
            float4 qv = qrow[s];                 // b128 broadcast
            float4 a = x0p[s ^ sw];              // b128, conflict-free
            float4 b = x1p[s ^ sw];
            s0 = fmaf(qv.x, a.x, fmaf(qv.y, a.y, fmaf(qv.z, a.z, fmaf(qv.w, a.w, s0))));
            s1 = fmaf(qv.x, b.x, fmaf(qv.y, b.y, fmaf(qv.z, b.z, fmaf(qv.w, b.w, s1))));
        }
    }
    s0 *= 0.125f;                                // 1/sqrt(64)
    s1 = (c1 < Cdim) ? s1 * 0.125f : -INFINITY;  // row 127 is pad

    // ---- wave-wide softmax over 127 values (2 per lane) ----
    float mx = fmaxf(s0, s1);
    #pragma unroll
    for (int mask = 32; mask >= 1; mask >>= 1)
        mx = fmaxf(mx, __shfl_xor(mx, mask, 64));
    float e0 = __expf(s0 - mx);
    float e1 = (c1 < Cdim) ? __expf(s1 - mx) : 0.f;
    float sum = e0 + e1;
    #pragma unroll
    for (int mask = 32; mask >= 1; mask >>= 1)
        sum += __shfl_xor(sum, mask, 64);
    float inv = 1.f / sum;
    w_lds[h * 128 + c0] = e0 * inv;
    w_lds[h * 128 + c1] = (c1 < Cdim) ? e1 * inv : 0.f;
    __syncthreads();

    // ---- wx[h][j] = sum_c w[c] * X[c][j]; lane = j ----
    float wxv = 0.f;
    {
        const float* wrow = w_lds + h * 128;
        const float* sXf = (const float*)sX4;
        int jq = lane >> 2, jr = lane & 3;
        #pragma unroll 8
        for (int c = 0; c < 128; ++c) {          // c=127: w=0 * pad=0
            float x = sXf[c * 64 + (((jq ^ (c & 7)) << 2) | jr)];
            wxv = fmaf(wrow[c], x, wxv);
        }
    }
    wx_lds[h * 64 + lane] = wxv;
    __syncthreads();

    // ---- out[h,k] = sum_j wx[h,j] * Wv[j, h*64+k]; lane = k ----
    float acc = 0.f;
    {
        const float* wxr = wx_lds + h * 64;
        const float* wvcol = Wv + h * 64 + lane;
        #pragma unroll 4
        for (int j = 0; j < 64; ++j)
            acc = fmaf(wxr[j], wvcol[j * HK], acc);  // coalesced, L1/L2-hot
    }
    out[(size_t)bt * HK + tid] = acc;
}

extern "C" void kernel_launch(void* const* d_in, const int* in_sizes, int n_in,
                              void* d_out, int out_size, void* d_ws, size_t ws_size,
                              hipStream_t stream) {
    const float* q_x  = (const float*)d_in[0];   // [16,128,256]
    const float* kv_x = (const float*)d_in[1];   // [16,128,127,64]
    const float* Wq   = (const float*)d_in[2];   // [256,256]
    const float* Wk   = (const float*)d_in[3];   // [64,256]
    const float* Wv   = (const float*)d_in[4];   // [64,256]
    float* out = (float*)d_out;                  // [16,128,256] f32

    float* M  = (float*)d_ws;                    // 256*256 floats
    float* qk = M + 256 * 256;                   // 2048*256 floats

    precompute_M<<<256, 256, 0, stream>>>(Wq, Wk, M);
    qk_gemm<<<256, 256, 0, stream>>>(q_x, M, qk);
    attn_main<<<Bdim * Tdim, 256, 0, stream>>>(kv_x, qk, Wv, out);
}

// Round 3
// 48.542 us; speedup vs baseline: 1.3245x; 1.3245x over previous
//
#include <hip/hip_runtime.h>
#include <math.h>

// Shapes (hard-coded per reference setup_inputs):
//   b=16, t=128, c=t-1=127, kv_dim=k=64, h=4, q_dim=256
#define Bdim 16
#define Tdim 128
#define Cdim 127
#define Hdim 4
#define QD   256
#define HK   256   // h*k

// ---------------------------------------------------------------------------
// K1: M[i, h*64+m] = sum_j Wq[i,h*64+j] * Wk[m,h*64+j]
// grid (128 i-pairs, 2 head-pairs); Wk head-pair slice staged in LDS with +1
// pad (banks (m+kk)%32 -> 2-way, free). All global reads/writes coalesced.
__global__ __launch_bounds__(256) void precompute_M(
        const float* __restrict__ Wq, const float* __restrict__ Wk,
        float* __restrict__ M) {
    __shared__ float wk_s[64][129];   // Wk[m][H*128+kk], padded
    __shared__ float wq_s[2][128];    // two Wq row-slices
    int I = blockIdx.x;               // i-pair
    int H = blockIdx.y;               // head-pair (heads 2H, 2H+1)
    int tid = threadIdx.x;

    #pragma unroll
    for (int it = 0; it < 8; ++it) {
        int flat = tid + it * 256;            // 2048 float4 total
        int m = flat >> 5, kq = flat & 31;    // 32 float4 per row-slice
        float4 v = *(const float4*)(Wk + m * HK + H * 128 + kq * 4);
        wk_s[m][kq*4+0] = v.x; wk_s[m][kq*4+1] = v.y;
        wk_s[m][kq*4+2] = v.z; wk_s[m][kq*4+3] = v.w;
    }
    if (tid < 64) {
        int r = tid >> 5, kq = tid & 31;
        float4 v = *(const float4*)(Wq + (size_t)(I*2+r) * HK + H * 128 + kq * 4);
        wq_s[r][kq*4+0] = v.x; wq_s[r][kq*4+1] = v.y;
        wq_s[r][kq*4+2] = v.z; wq_s[r][kq*4+3] = v.w;
    }
    __syncthreads();

    int r = tid >> 7, hh = (tid >> 6) & 1, m = tid & 63;  // r,hh wave-uniform
    float acc = 0.f;
    #pragma unroll 8
    for (int j = 0; j < 64; ++j)
        acc = fmaf(wq_s[r][hh*64+j], wk_s[m][hh*64+j], acc);  // bcast + 2-way
    M[(size_t)(I*2+r) * HK + H * 128 + hh * 64 + m] = acc;
}

// ---------------------------------------------------------------------------
// K2: qk = q_x @ M, K-split into NS partial buffers (summed in attn_main).
// grid (128 row-blocks, NS); 16 rows x 256 cols per block; thread = column.
template <int NS>
__global__ __launch_bounds__(256) void qk_gemm(
        const float* __restrict__ q_x,
        const float* __restrict__ M,
        float* __restrict__ part) {
    const int KLEN = 256 / NS;
    __shared__ __align__(16) float q_s[16][256 / NS];
    int RB = blockIdx.x;
    int S  = blockIdx.y;
    int tid = threadIdx.x;

    for (int f = tid; f < 16 * KLEN / 4; f += 256) {
        int r = f / (KLEN / 4), kq = f % (KLEN / 4);
        *(float4*)&q_s[r][kq*4] =
            *(const float4*)(q_x + (size_t)(RB*16 + r) * QD + S * KLEN + kq * 4);
    }
    __syncthreads();

    float acc[16];
    #pragma unroll
    for (int r = 0; r < 16; ++r) acc[r] = 0.f;

    for (int kk = 0; kk < KLEN / 4; ++kk) {
        int k = S * KLEN + kk * 4;
        float m0 = M[(size_t)(k+0) * HK + tid];   // coalesced, L2-hot
        float m1 = M[(size_t)(k+1) * HK + tid];
        float m2 = M[(size_t)(k+2) * HK + tid];
        float m3 = M[(size_t)(k+3) * HK + tid];
        #pragma unroll
        for (int r = 0; r < 16; ++r) {
            float4 qv = *(const float4*)&q_s[r][kk*4];   // b128 broadcast
            acc[r] = fmaf(qv.x, m0, fmaf(qv.y, m1, fmaf(qv.z, m2, fmaf(qv.w, m3, acc[r]))));
        }
    }
    float* dst = part + (size_t)S * (Bdim*Tdim*HK) + (size_t)RB * 16 * HK + tid;
    #pragma unroll
    for (int r = 0; r < 16; ++r) dst[r * HK] = acc[r];
}

// ---------------------------------------------------------------------------
// K3: per (b,t): scores -> softmax -> wx (context contraction) -> V-proj.
// X row-major in LDS, float4 chunks, XOR slot swizzle phys = log ^ (c&7).
// Staged via global_load_lds (linear LDS dest, pre-swizzled global source).
__global__ __launch_bounds__(256) void attn_main(
        const float* __restrict__ kv_x,
        const float* __restrict__ qk_p, int nsplit,
        const float* __restrict__ Wv,
        float* __restrict__ out) {
    __shared__ __align__(16) float4 sX4[128 * 16];  // 32 KB; row 127 zeroed
    __shared__ __align__(16) float qk_s[HK];
    __shared__ __align__(16) float w_lds[Hdim * 128];
    __shared__ __align__(16) float wx_lds[Hdim * 64];

    int bt  = blockIdx.x;
    int tid = threadIdx.x;
    int h = tid >> 6, lane = tid & 63;

    // ---- async stage: LDS linear, global source pre-swizzled ----
    const float4* Xg = (const float4*)(kv_x + (size_t)bt * (Cdim * 64));
    #pragma unroll
    for (int it = 0; it < 8; ++it) {
        int l = tid + it * 256;                 // linear LDS chunk index
        if (l < Cdim * 16) {
            int c = l >> 4, p = l & 15;
            __builtin_amdgcn_global_load_lds(
                (const __attribute__((address_space(1))) void*)(Xg + (c << 4) + (p ^ (c & 7))),
                (__attribute__((address_space(3))) void*)(sX4 + l), 16, 0, 0);
        }
    }
    if (tid < 64) ((float*)sX4)[Cdim * 64 + tid] = 0.f;   // zero pad row 127
    {
        float q = 0.f;
        for (int s = 0; s < nsplit; ++s)
            q += qk_p[(size_t)s * (Bdim*Tdim*HK) + (size_t)bt * HK + tid];
        qk_s[tid] = q;
    }
    __syncthreads();

    // ---- scores: lane handles c0 = lane, c1 = lane+64 ----
    int c0 = lane, c1 = lane + 64;
    int sw = lane & 7;                           // (c0&7) == (c1&7)
    float s0 = 0.f, s1 = 0.f;
    {
        const float4* qrow = (const float4*)(qk_s + h * 64);
        const float4* x0p = sX4 + c0 * 16;
        const float4* x1p = sX4 + c1 * 16;
        #pragma unroll
        for (int s = 0; s < 16; ++s) {
            float4 qv = qrow[s];                 // b128 broadcast
            float4 a = x0p[s ^ sw];              // balanced 8-group access
            float4 b = x1p[s ^ sw];
            s0 = fmaf(qv.x, a.x, fmaf(qv.y, a.y, fmaf(qv.z, a.z, fmaf(qv.w, a.w, s0))));
            s1 = fmaf(qv.x, b.x, fmaf(qv.y, b.y, fmaf(qv.z, b.z, fmaf(qv.w, b.w, s1))));
        }
    }
    s0 *= 0.125f;                                // 1/sqrt(64)
    s1 = (c1 < Cdim) ? s1 * 0.125f : -INFINITY;

    // ---- wave-wide softmax over 127 values (2 per lane) ----
    float mx = fmaxf(s0, s1);
    #pragma unroll
    for (int mask = 32; mask >= 1; mask >>= 1)
        mx = fmaxf(mx, __shfl_xor(mx, mask, 64));
    float e0 = __expf(s0 - mx);
    float e1 = (c1 < Cdim) ? __expf(s1 - mx) : 0.f;
    float sum = e0 + e1;
    #pragma unroll
    for (int mask = 32; mask >= 1; mask >>= 1)
        sum += __shfl_xor(sum, mask, 64);
    float inv = 1.f / sum;
    w_lds[h * 128 + c0] = e0 * inv;
    w_lds[h * 128 + c1] = (c1 < Cdim) ? e1 * inv : 0.f;
    __syncthreads();

    // ---- wx[h][j] = sum_c w[c]*X[c][j], lane = (cgrp, jgrp) ----
    // lane covers c in [cgrp*8, cgrp*8+8) (rotated order keeps banks balanced)
    // and j in [jgrp*16, jgrp*16+16) as 4 float4 accumulators.
    int cgrp = lane >> 2, jgrp = lane & 3;
    float4 a0 = {0,0,0,0}, a1 = {0,0,0,0}, a2 = {0,0,0,0}, a3 = {0,0,0,0};
    #pragma unroll
    for (int i = 0; i < 8; ++i) {
        int ip = (i + cgrp) & 7;                 // rotated c-order
        int c  = cgrp * 8 + ip;                  // c&7 == ip
        float wv = w_lds[h * 128 + c];
        const float4* row = sX4 + c * 16;
        float4 x0 = row[(jgrp*4 + 0) ^ ip];      // phys = log ^ (c&7)
        float4 x1 = row[(jgrp*4 + 1) ^ ip];
        float4 x2 = row[(jgrp*4 + 2) ^ ip];
        float4 x3 = row[(jgrp*4 + 3) ^ ip];
        a0.x = fmaf(wv, x0.x, a0.x); a0.y = fmaf(wv, x0.y, a0.y);
        a0.z = fmaf(wv, x0.z, a0.z); a0.w = fmaf(wv, x0.w, a0.w);
        a1.x = fmaf(wv, x1.x, a1.x); a1.y = fmaf(wv, x1.y, a1.y);
        a1.z = fmaf(wv, x1.z, a1.z); a1.w = fmaf(wv, x1.w, a1.w);
        a2.x = fmaf(wv, x2.x, a2.x); a2.y = fmaf(wv, x2.y, a2.y);
        a2.z = fmaf(wv, x2.z, a2.z); a2.w = fmaf(wv, x2.w, a2.w);
        a3.x = fmaf(wv, x3.x, a3.x); a3.y = fmaf(wv, x3.y, a3.y);
        a3.z = fmaf(wv, x3.z, a3.z); a3.w = fmaf(wv, x3.w, a3.w);
    }
    // reduce across the 16 cgrp lanes sharing this jgrp (bits 2..5)
    #pragma unroll
    for (int mask = 4; mask <= 32; mask <<= 1) {
        a0.x += __shfl_xor(a0.x, mask, 64); a0.y += __shfl_xor(a0.y, mask, 64);
        a0.z += __shfl_xor(a0.z, mask, 64); a0.w += __shfl_xor(a0.w, mask, 64);
        a1.x += __shfl_xor(a1.x, mask, 64); a1.y += __shfl_xor(a1.y, mask, 64);
        a1.z += __shfl_xor(a1.z, mask, 64); a1.w += __shfl_xor(a1.w, mask, 64);
        a2.x += __shfl_xor(a2.x, mask, 64); a2.y += __shfl_xor(a2.y, mask, 64);
        a2.z += __shfl_xor(a2.z, mask, 64); a2.w += __shfl_xor(a2.w, mask, 64);
        a3.x += __shfl_xor(a3.x, mask, 64); a3.y += __shfl_xor(a3.y, mask, 64);
        a3.z += __shfl_xor(a3.z, mask, 64); a3.w += __shfl_xor(a3.w, mask, 64);
    }
    if (cgrp == 0) {
        float4* wdst = (float4*)(wx_lds + h * 64 + jgrp * 16);
        wdst[0] = a0; wdst[1] = a1; wdst[2] = a2; wdst[3] = a3;
    }
    __syncthreads();

    // ---- out[h,k] = sum_j wx[h,j] * Wv[j, h*64+k]; lane = k ----
    float acc = 0.f;
    {
        const float* wxr = wx_lds + h * 64;
        const float* wvcol = Wv + h * 64 + lane;
        #pragma unroll 4
        for (int j = 0; j < 64; ++j)
            acc = fmaf(wxr[j], wvcol[(size_t)j * HK], acc);  // coalesced, L2-hot
    }
    out[(size_t)bt * HK + tid] = acc;
}

extern "C" void kernel_launch(void* const* d_in, const int* in_sizes, int n_in,
                              void* d_out, int out_size, void* d_ws, size_t ws_size,
                              hipStream_t stream) {
    const float* q_x  = (const float*)d_in[0];   // [16,128,256]
    const float* kv_x = (const float*)d_in[1];   // [16,128,127,64]
    const float* Wq   = (const float*)d_in[2];   // [256,256]
    const float* Wk   = (const float*)d_in[3];   // [64,256]
    const float* Wv   = (const float*)d_in[4];   // [64,256]
    float* out = (float*)d_out;                  // [16,128,256] f32

    float* M     = (float*)d_ws;                 // 256*256 floats
    float* parts = M + 256 * 256;                // NS * 2048*256 floats

    size_t need4 = (size_t)(256*256 + 4 * Bdim*Tdim*HK) * sizeof(float);
    int nsplit = (ws_size >= need4) ? 4 : 1;

    precompute_M<<<dim3(128, 2), 256, 0, stream>>>(Wq, Wk, M);
    if (nsplit == 4)
        qk_gemm<4><<<dim3(128, 4), 256, 0, stream>>>(q_x, M, parts);
    else
        qk_gemm<1><<<dim3(128, 1), 256, 0, stream>>>(q_x, M, parts);
    attn_main<<<Bdim * Tdim, 256, 0, stream>>>(kv_x, parts, nsplit, Wv, out);
}